// Round 7
// baseline (405.486 us; speedup 1.0000x reference)
//
#include <hip/hip_runtime.h>

#define NNODES 50000
#define NEDGES 640000
#define D 128

typedef unsigned short u16;
typedef unsigned int u32;
typedef __bf16 bf16x8 __attribute__((ext_vector_type(8)));
typedef float f32x4 __attribute__((ext_vector_type(4)));
union AB { uint4 u4; bf16x8 f; };

__device__ __forceinline__ u16 f2b(float f) {
    u32 u = __float_as_uint(f);
    return (u16)((u + 0x7fffu + ((u >> 16) & 1u)) >> 16);
}
__device__ __forceinline__ u32 pack2(float lo, float hi) {
    return (u32)f2b(lo) | ((u32)f2b(hi) << 16);
}
__device__ __forceinline__ float blo(u32 v) { return __uint_as_float(v << 16); }
__device__ __forceinline__ float bhi(u32 v) { return __uint_as_float(v & 0xffff0000u); }

__device__ __forceinline__ void acc8(float* a, uint4 v) {
    a[0] += blo(v.x); a[1] += bhi(v.x);
    a[2] += blo(v.y); a[3] += bhi(v.y);
    a[4] += blo(v.z); a[5] += bhi(v.z);
    a[6] += blo(v.w); a[7] += bhi(v.w);
}

// ---------------- CSR build ----------------

__global__ void k_hist(const int* __restrict__ dst, int* __restrict__ cnt) {
    int e = blockIdx.x * 256 + threadIdx.x;
    if (e < NEDGES) atomicAdd(&cnt[dst[e]], 1);
}

__global__ void k_scan1(const int* __restrict__ cnt, int* __restrict__ rp,
                        int* __restrict__ bsum) {
    __shared__ int s[256];
    int tid = threadIdx.x;
    int i = blockIdx.x * 256 + tid;
    int v = (i < NNODES) ? cnt[i] : 0;
    s[tid] = v;
    __syncthreads();
    for (int off = 1; off < 256; off <<= 1) {
        int t = (tid >= off) ? s[tid - off] : 0;
        __syncthreads();
        s[tid] += t;
        __syncthreads();
    }
    if (i < NNODES) rp[i] = s[tid] - v;
    if (tid == 255) bsum[blockIdx.x] = s[255];
}

__global__ void k_scan2(int* __restrict__ bsum, int nb) {
    __shared__ int s[256];
    int tid = threadIdx.x;
    int v = (tid < nb) ? bsum[tid] : 0;
    s[tid] = v;
    __syncthreads();
    for (int off = 1; off < 256; off <<= 1) {
        int t = (tid >= off) ? s[tid - off] : 0;
        __syncthreads();
        s[tid] += t;
        __syncthreads();
    }
    if (tid < nb) bsum[tid] = s[tid] - v;
}

__global__ void k_add(int* __restrict__ rp, const int* __restrict__ bsum) {
    int i = blockIdx.x * 256 + threadIdx.x;
    if (i < NNODES) rp[i] += bsum[blockIdx.x];
    if (i == 0) rp[NNODES] = NEDGES;
}

__global__ void k_scatter(const int* __restrict__ src, const int* __restrict__ dst,
                          const int* __restrict__ rp, int* __restrict__ cnt,
                          int* __restrict__ srcs) {
    int e = blockIdx.x * 256 + threadIdx.x;
    if (e < NEDGES) {
        int dn = dst[e];
        int old = atomicSub(&cnt[dn], 1);
        srcs[rp[dn] + old - 1] = src[e];
    }
}

// ---------------- weight prep (transpose->bf16) + x conversion, merged ----------------
__global__ void k_prep(const float* __restrict__ W1, const float* __restrict__ W2,
                       const float* __restrict__ fw, const float* __restrict__ x,
                       u16* __restrict__ wT1, u16* __restrict__ wT2,
                       u16* __restrict__ fwTc, u32* __restrict__ xb) {
    int idx = blockIdx.x * 256 + threadIdx.x;  // grid covers NNODES*64
    if (idx < 3 * 16384) {
        int l = idx >> 14, r = idx & 16383, n = r >> 7, k = r & 127;
        wT1[idx] = f2b(W1[l * 16384 + k * 128 + n]);
        wT2[idx] = f2b(W2[l * 16384 + k * 128 + n]);
    }
    if (idx < 4 * 16384) {
        int ch = idx >> 14, r = idx & 16383, n = r >> 7, k = r & 127;
        fwTc[idx] = f2b(fw[(ch * 128 + k) * 128 + n]);
    }
    if (idx < NNODES * 64) {
        float2 v = ((const float2*)x)[idx];
        xb[idx] = pack2(v.x, v.y);
    }
}

// ---------------- aggregation (unchanged from round 5) ----------------
__global__ void k_agg(const uint4* __restrict__ h4, const int* __restrict__ rp,
                      const int* __restrict__ srcs, const float* __restrict__ epsp,
                      uint4* __restrict__ z4) {
    int tid = threadIdx.x;
    int c = tid & 15;
    int node = (blockIdx.x * 256 + tid) >> 4;
    int gbase = tid & 48;
    float sc = 1.0f + epsp[0];

    uint4 sv = h4[node * 16 + c];
    float acc[8];
    acc[0] = sc * blo(sv.x); acc[1] = sc * bhi(sv.x);
    acc[2] = sc * blo(sv.y); acc[3] = sc * bhi(sv.y);
    acc[4] = sc * blo(sv.z); acc[5] = sc * bhi(sv.z);
    acc[6] = sc * blo(sv.w); acc[7] = sc * bhi(sv.w);

    int beg = rp[node], end = rp[node + 1];
    for (int base = beg; base < end; base += 16) {
        int n = end - base; if (n > 16) n = 16;
        int myidx = (base + c < end) ? srcs[base + c] : 0;
        int j = 0;
        for (; j + 8 <= n; j += 8) {
            int s0 = __shfl(myidx, gbase + j + 0, 64);
            int s1 = __shfl(myidx, gbase + j + 1, 64);
            int s2 = __shfl(myidx, gbase + j + 2, 64);
            int s3 = __shfl(myidx, gbase + j + 3, 64);
            int s4 = __shfl(myidx, gbase + j + 4, 64);
            int s5 = __shfl(myidx, gbase + j + 5, 64);
            int s6 = __shfl(myidx, gbase + j + 6, 64);
            int s7 = __shfl(myidx, gbase + j + 7, 64);
            uint4 v0 = h4[s0 * 16 + c]; uint4 v1 = h4[s1 * 16 + c];
            uint4 v2 = h4[s2 * 16 + c]; uint4 v3 = h4[s3 * 16 + c];
            uint4 v4 = h4[s4 * 16 + c]; uint4 v5 = h4[s5 * 16 + c];
            uint4 v6 = h4[s6 * 16 + c]; uint4 v7 = h4[s7 * 16 + c];
            acc8(acc, v0); acc8(acc, v1); acc8(acc, v2); acc8(acc, v3);
            acc8(acc, v4); acc8(acc, v5); acc8(acc, v6); acc8(acc, v7);
        }
        for (; j + 4 <= n; j += 4) {
            int s0 = __shfl(myidx, gbase + j + 0, 64);
            int s1 = __shfl(myidx, gbase + j + 1, 64);
            int s2 = __shfl(myidx, gbase + j + 2, 64);
            int s3 = __shfl(myidx, gbase + j + 3, 64);
            uint4 v0 = h4[s0 * 16 + c]; uint4 v1 = h4[s1 * 16 + c];
            uint4 v2 = h4[s2 * 16 + c]; uint4 v3 = h4[s3 * 16 + c];
            acc8(acc, v0); acc8(acc, v1); acc8(acc, v2); acc8(acc, v3);
        }
        for (; j < n; ++j) {
            int s0 = __shfl(myidx, gbase + j, 64);
            uint4 v0 = h4[s0 * 16 + c];
            acc8(acc, v0);
        }
    }

    uint4 o;
    o.x = pack2(acc[0], acc[1]); o.y = pack2(acc[2], acc[3]);
    o.z = pack2(acc[4], acc[5]); o.w = pack2(acc[6], acc[7]);
    z4[node * 16 + c] = o;
}

// ---------------- per-wave MLP: no barriers, no shared W staging ----------------
// Each wave owns 16 rows (50000 = 3125 waves exactly). B-frags straight from
// global (L2-hot weights). T transform via private per-wave LDS scratch
// (row stride 136 u16 -> 16B-aligned b128 reads), same-wave DS ordering only.
#define SROW 136
__launch_bounds__(256)
__global__ void k_mlp(const u16* __restrict__ A, const u16* __restrict__ wT1g,
                      const float* __restrict__ b1, const u16* __restrict__ wT2g,
                      const float* __restrict__ b2, u16* __restrict__ H) {
    __shared__ u16 scratch[4][16 * SROW];  // 4 x 4.25 KB
    int tid = threadIdx.x;
    int wave = tid >> 6, lane = tid & 63, l16 = lane & 15, quad = lane >> 4;
    int wid = blockIdx.x * 4 + wave;
    if (wid * 16 >= NNODES) return;
    int r0 = wid * 16;
    u16* sc = scratch[wave];

    AB a[4];
#pragma unroll
    for (int kb = 0; kb < 4; ++kb)
        a[kb].u4 = *(const uint4*)&A[(r0 + l16) * 128 + kb * 32 + quad * 8];

    f32x4 acc[8];
#pragma unroll
    for (int col = 0; col < 8; ++col) {
        float bv = b1[col * 16 + l16];
        acc[col] = (f32x4){bv, bv, bv, bv};
    }
#pragma unroll
    for (int col = 0; col < 8; ++col) {
        AB b[4];
#pragma unroll
        for (int kb = 0; kb < 4; ++kb)
            b[kb].u4 = *(const uint4*)&wT1g[(col * 16 + l16) * 128 + kb * 32 + quad * 8];
#pragma unroll
        for (int kb = 0; kb < 4; ++kb)
            acc[col] = __builtin_amdgcn_mfma_f32_16x16x32_bf16(a[kb].f, b[kb].f, acc[col], 0, 0, 0);
    }

    // T = relu -> scratch (C-layout scalar stores)
#pragma unroll
    for (int col = 0; col < 8; ++col)
#pragma unroll
        for (int r = 0; r < 4; ++r)
            sc[(quad * 4 + r) * SROW + col * 16 + l16] = f2b(fmaxf(acc[col][r], 0.f));

    // A-frags for GEMM2 (same wave; DS ops are in-order within a wave)
    AB a2[4];
#pragma unroll
    for (int kb = 0; kb < 4; ++kb)
        a2[kb].u4 = *(const uint4*)&sc[l16 * SROW + kb * 32 + quad * 8];

#pragma unroll
    for (int col = 0; col < 8; ++col) {
        float bv = b2[col * 16 + l16];
        acc[col] = (f32x4){bv, bv, bv, bv};
    }
#pragma unroll
    for (int col = 0; col < 8; ++col) {
        AB b[4];
#pragma unroll
        for (int kb = 0; kb < 4; ++kb)
            b[kb].u4 = *(const uint4*)&wT2g[(col * 16 + l16) * 128 + kb * 32 + quad * 8];
#pragma unroll
        for (int kb = 0; kb < 4; ++kb)
            acc[col] = __builtin_amdgcn_mfma_f32_16x16x32_bf16(a2[kb].f, b[kb].f, acc[col], 0, 0, 0);
    }

    // H = relu -> scratch -> coalesced global.
    // 16 rows x 16 uint4-chunks = 256 chunks -> 4 passes of 64 lanes.
#pragma unroll
    for (int col = 0; col < 8; ++col)
#pragma unroll
        for (int r = 0; r < 4; ++r)
            sc[(quad * 4 + r) * SROW + col * 16 + l16] = f2b(fmaxf(acc[col][r], 0.f));

#pragma unroll
    for (int p = 0; p < 4; ++p) {
        int idx = p * 64 + lane;       // 0..255
        int row = idx >> 4, ch = idx & 15;
        uint4 v = *(const uint4*)&sc[row * SROW + ch * 8];
        *(uint4*)&H[(r0 + row) * 128 + ch * 8] = v;
    }
}

// ---------------- per-wave final: out = concat(x,h1,h2,h3) @ fw + fb ----------------
__launch_bounds__(256)
__global__ void k_final(const u16* __restrict__ xb, const u16* __restrict__ h1,
                        const u16* __restrict__ h2b, const u16* __restrict__ h3,
                        const u16* __restrict__ fwTc, const float* __restrict__ fb,
                        float* __restrict__ out) {
    int tid = threadIdx.x;
    int wave = tid >> 6, lane = tid & 63, l16 = lane & 15, quad = lane >> 4;
    int wid = blockIdx.x * 4 + wave;
    if (wid * 16 >= NNODES) return;
    int r0 = wid * 16;

    f32x4 acc[8];
#pragma unroll
    for (int col = 0; col < 8; ++col) {
        float bv = fb[col * 16 + l16];
        acc[col] = (f32x4){bv, bv, bv, bv};
    }

    const u16* chin[4] = {xb, h1, h2b, h3};
#pragma unroll
    for (int chn = 0; chn < 4; ++chn) {
        const u16* cp = chin[chn];
        const u16* wp = fwTc + chn * 16384;
        AB a[4];
#pragma unroll
        for (int kb = 0; kb < 4; ++kb)
            a[kb].u4 = *(const uint4*)&cp[(r0 + l16) * 128 + kb * 32 + quad * 8];
#pragma unroll
        for (int col = 0; col < 8; ++col) {
            AB b[4];
#pragma unroll
            for (int kb = 0; kb < 4; ++kb)
                b[kb].u4 = *(const uint4*)&wp[(col * 16 + l16) * 128 + kb * 32 + quad * 8];
#pragma unroll
            for (int kb = 0; kb < 4; ++kb)
                acc[col] = __builtin_amdgcn_mfma_f32_16x16x32_bf16(a[kb].f, b[kb].f, acc[col], 0, 0, 0);
        }
    }

#pragma unroll
    for (int col = 0; col < 8; ++col)
#pragma unroll
        for (int r = 0; r < 4; ++r)
            out[(r0 + quad * 4 + r) * 128 + col * 16 + l16] = acc[col][r];
}

extern "C" void kernel_launch(void* const* d_in, const int* in_sizes, int n_in,
                              void* d_out, int out_size, void* d_ws, size_t ws_size,
                              hipStream_t stream) {
    const float* x   = (const float*)d_in[0];
    const int*   ei  = (const int*)d_in[1];
    const float* W1  = (const float*)d_in[2];
    const float* b1  = (const float*)d_in[3];
    const float* W2  = (const float*)d_in[4];
    const float* b2  = (const float*)d_in[5];
    const float* eps = (const float*)d_in[6];
    const float* fw  = (const float*)d_in[7];
    const float* fb  = (const float*)d_in[8];
    float* out = (float*)d_out;

    const int* srcA = ei;
    const int* dstA = ei + NEDGES;

    char* p = (char*)d_ws;
    size_t off = 0;
    auto take = [&](size_t bytes) {
        char* r = p + off;
        off = (off + bytes + 255) & ~(size_t)255;
        return r;
    };
    int* rp   = (int*)take((NNODES + 1) * sizeof(int));
    int* cnt  = (int*)take(NNODES * sizeof(int));
    int* bsum = (int*)take(256 * sizeof(int));
    int* srcs = (int*)take(NEDGES * sizeof(int));
    u16* wT1  = (u16*)take(3 * 16384 * sizeof(u16));
    u16* wT2  = (u16*)take(3 * 16384 * sizeof(u16));
    u16* fwTc = (u16*)take(4 * 16384 * sizeof(u16));
    u16* xb   = (u16*)take((size_t)NNODES * D * sizeof(u16));
    u16* zb   = (u16*)take((size_t)NNODES * D * sizeof(u16));
    u16* hb1  = (u16*)take((size_t)NNODES * D * sizeof(u16));
    u16* hb2  = (u16*)take((size_t)NNODES * D * sizeof(u16));
    u16* hb3  = (u16*)take((size_t)NNODES * D * sizeof(u16));
    (void)ws_size; (void)in_sizes; (void)n_in; (void)out_size;

    hipMemsetAsync(cnt, 0, NNODES * sizeof(int), stream);

    int nb = (NNODES + 255) / 256;
    k_hist<<<(NEDGES + 255) / 256, 256, 0, stream>>>(dstA, cnt);
    k_scan1<<<nb, 256, 0, stream>>>(cnt, rp, bsum);
    k_scan2<<<1, 256, 0, stream>>>(bsum, nb);
    k_add<<<nb, 256, 0, stream>>>(rp, bsum);
    k_scatter<<<(NEDGES + 255) / 256, 256, 0, stream>>>(srcA, dstA, rp, cnt, srcs);
    k_prep<<<(NNODES * 64 + 255) / 256, 256, 0, stream>>>(W1, W2, fw, x, wT1, wT2, fwTc, (u32*)xb);

    const u16* hin = xb;
    u16* houts[3] = {hb1, hb2, hb3};
    int gw = (3125 + 3) / 4;  // 782 blocks of 4 waves (16 rows each)
    for (int l = 0; l < 3; ++l) {
        k_agg<<<NNODES * 16 / 256, 256, 0, stream>>>((const uint4*)hin, rp, srcs, eps + l, (uint4*)zb);
        k_mlp<<<gw, 256, 0, stream>>>(zb, wT1 + l * 16384, b1 + l * D,
                                      wT2 + l * 16384, b2 + l * D, houts[l]);
        hin = houts[l];
    }
    k_final<<<gw, 256, 0, stream>>>(xb, hb1, hb2, hb3, fwTc, fb, out);
}